// Round 5
// baseline (365.817 us; speedup 1.0000x reference)
//
#include <hip/hip_runtime.h>

// Gabor layer: out[i,o] = sin(x[i]·W[o] + b[o]) * exp(-0.5*||x[i]-mu[o]||^2 * gamma[o])
// B=262144 rows, O=256 outputs, D=2.  Output 256 MiB f32 -> write-bound.
//
// R5 = MEASUREMENT ROUND. Four structurally different kernels (private windows,
// 4KiB NT bursts, 8 waves/SIMD, slab sweep) all landed at dur_us ~268-281.
// The gabor dispatch has never appeared in top-5 (all fills, 161-171us), so
// kernel < 161us, but its exact time is UNKNOWN — "kernel = dur - fill = 105us"
// is an inference. This round launches the IDENTICAL kernel 3x back-to-back
// (idempotent, deterministic, stream-serialized):
//     T_kernel = (dur_us - 268) / 2
// H1 (kernel ~105us @2.5TB/s): expect dur ~478 -> keep optimizing the kernel.
// H2 (kernel ~45-60us @ write roofline; residual is harness overhead):
//     expect dur ~355-370 -> call ROOFLINE next round.

#define NROWS 262144
#define NOUT  256
#define GRID  2048
#define RPI   16                       // rows per block per iteration
#define NIT   (NROWS / (GRID * RPI))   // 8
#define INV2PI 0.15915494309189535f
#define LOG2E  1.4426950408889634f

typedef float v4f __attribute__((ext_vector_type(4)));

#if __has_builtin(__builtin_amdgcn_exp2f)
#define EXP2F(v) __builtin_amdgcn_exp2f(v)
#else
#define EXP2F(v) exp2f(v)
#endif

__global__ __launch_bounds__(256, 8)
void gabor_kernel(const float* __restrict__ x,
                  const float* __restrict__ W,
                  const float* __restrict__ b,
                  const float* __restrict__ mu,
                  const float* __restrict__ gamma,
                  float* __restrict__ out)
{
    const int tid  = threadIdx.x;
    const int oq   = (tid & 63) * 4;   // this lane's 4 consecutive outputs
    const int wsub = tid >> 6;         // wave id 0..3 (uniform per wave)

    float W0[4], W1[4], bb[4], mu0[4], mu1[4], ng[4];
#pragma unroll
    for (int j = 0; j < 4; ++j) {
        const int o = oq + j;
        W0[j]  = W[o * 2 + 0] * INV2PI;
        W1[j]  = W[o * 2 + 1] * INV2PI;
        bb[j]  = b[o] * INV2PI;
        mu0[j] = mu[o * 2 + 0];
        mu1[j] = mu[o * 2 + 1];
        ng[j]  = -0.5f * LOG2E * gamma[o];
    }

    const float4* xv = reinterpret_cast<const float4*>(x);   // 2 rows / float4

    auto do_row = [&](float rx, float ry, float* dst) {
        v4f res;
#pragma unroll
        for (int j = 0; j < 4; ++j) {
            const float lin = __fmaf_rn(rx, W0[j], __fmaf_rn(ry, W1[j], bb[j]));
            const float dx  = rx - mu0[j];
            const float dy  = ry - mu1[j];
            const float d2  = __fmaf_rn(dy, dy, dx * dx);
            res[j] = __builtin_amdgcn_sinf(lin) * EXP2F(d2 * ng[j]);
        }
        *reinterpret_cast<v4f*>(dst) = res;
    };

#pragma unroll 2
    for (int it = 0; it < NIT; ++it) {
        const int r = (it * GRID + blockIdx.x) * RPI + wsub * 4;
        const float4 xa = xv[(r >> 1) + 0];      // rows r, r+1 (broadcast)
        const float4 xb = xv[(r >> 1) + 1];      // rows r+2, r+3
        float* orow = out + (size_t)r * NOUT + oq;

        do_row(xa.x, xa.y, orow);
        do_row(xa.z, xa.w, orow + 1 * NOUT);
        do_row(xb.x, xb.y, orow + 2 * NOUT);
        do_row(xb.z, xb.w, orow + 3 * NOUT);
    }
}

extern "C" void kernel_launch(void* const* d_in, const int* in_sizes, int n_in,
                              void* d_out, int out_size, void* d_ws, size_t ws_size,
                              hipStream_t stream)
{
    const float* x     = (const float*)d_in[0];  // (B, 2)
    const float* W     = (const float*)d_in[1];  // (O, 2)
    const float* b     = (const float*)d_in[2];  // (O,)
    const float* mu    = (const float*)d_in[3];  // (1, O, 2)
    const float* gamma = (const float*)d_in[4];  // (O,)
    float* out = (float*)d_out;                  // (B, O)

    // MEASUREMENT: 3 identical idempotent launches. T_kernel = (dur - 268)/2.
    gabor_kernel<<<GRID, 256, 0, stream>>>(x, W, b, mu, gamma, out);
    gabor_kernel<<<GRID, 256, 0, stream>>>(x, W, b, mu, gamma, out);
    gabor_kernel<<<GRID, 256, 0, stream>>>(x, W, b, mu, gamma, out);
}